// Round 6
// baseline (1488.975 us; speedup 1.0000x reference)
//
#include <hip/hip_runtime.h>

#define NB 1024
#define NT 256
#define IND 10
#define HID 64
#define WPJ 404   // packed weight floats per output column j

// ---------------------------------------------------------------------------
// Weight repack (layout unchanged from r2..r5):
//   0..119   : Ws  (W1[11+q]+W1[132+q]) in payload order [A(10),B(10),C(100)]
//   120..239 : Wb  (W1[253+q])   gated by rel0
//   240..359 : Wc  (W1[374+q])   gated by rel1
//   360..369 : wdA, 370: wdB0, 371..375: wdC   (rel2-gated 17-term)
//   376..385 : wrel (sig1), 386..395: wf (features)
//   396..399 : tt coefs (ws,wb,wc,wd), 400: w_one, 401: b1[j], 402..403 pad
// payload order k: k<10: A_c = r*inc_c ; k in [10,20): B_i = rel_i ;
//                  k in [20,120): C_{i,c} = rel_i*inc_c at k = 20+10i+c
// ---------------------------------------------------------------------------
__device__ __forceinline__ int qmap(int kk) {
    if (kk < 10) return 1 + kk;
    if (kk < 20) return 11 * (kk - 10 + 1);
    int i = (kk - 20) / 10, c = (kk - 20) % 10;
    return 11 * (i + 1) + 1 + c;
}

__global__ void pack_kernel(const float* __restrict__ W1, const float* __restrict__ b1,
                            float* __restrict__ Wr) {
    int idx = blockIdx.x * 256 + threadIdx.x;
    if (idx >= 64 * WPJ) return;
    int j = idx / WPJ, k = idx % WPJ;
    float v = 0.f;
    if (k < 120)       { int q = qmap(k);       v = W1[(11+q)*64+j] + W1[(132+q)*64+j]; }
    else if (k < 240)  { int q = qmap(k - 120); v = W1[(253+q)*64+j]; }
    else if (k < 360)  { int q = qmap(k - 240); v = W1[(374+q)*64+j]; }
    else if (k < 370)  { v = W1[(495 + 1 + (k-360))*64 + j]; }
    else if (k == 370) { v = W1[(495 + 11)*64 + j]; }
    else if (k < 376)  { v = W1[(495 + 12 + (k-371))*64 + j]; }
    else if (k < 386)  { v = W1[(1 + (k-376))*64 + j]; }
    else if (k < 396)  { v = W1[(512 + (k-386))*64 + j]; }
    else if (k == 396) { v = W1[11*64+j] + W1[132*64+j]; }
    else if (k == 397) { v = W1[253*64+j]; }
    else if (k == 398) { v = W1[374*64+j]; }
    else if (k == 399) { v = W1[495*64+j]; }
    else if (k == 400) { v = W1[0*64+j]; }
    else if (k == 401) { v = b1[j]; }
    Wr[idx] = v;
}

// ---------------------------------------------------------------------------
// presig v2: block = batch, 4 waves, 4 t-tiles of 64.
// Scan phase: wave w scans payload components [30w,30w+30) across the tile's
//   64 lanes (only 30 floats live per thread -> no spill), running cross-tile
//   base kept in 30 lane-uniform VGPRs per wave, result -> LDS sP[k][t].
// j-phase: wave w computes j in [16w,16w+16); P chunks (30) re-read from LDS
//   once per chunk and reused over 16 j; weights via uniform s_loads
//   (readfirstlane'd jbase). Output staged in LDS, coalesced copy-out.
// ---------------------------------------------------------------------------
__global__ __launch_bounds__(256, 1) void presig2_kernel(
    const float* __restrict__ features, const float* __restrict__ Wr,
    float* __restrict__ pre1) {
    const int b = blockIdx.x;
    const int tid = threadIdx.x;
    const int l = tid & 63;                                   // lane = t within tile
    const int wu = __builtin_amdgcn_readfirstlane(tid >> 6);  // wave id (uniform SGPR)

    __shared__ __align__(16) float sFt[65 * IND];   // feature rows t0..t0+64 (clamped)
    __shared__ __align__(16) float sP[120 * 65];    // sP[k*65 + t], pad stride 65
    __shared__ __align__(16) float sPre[64 * 65];   // sPre[t*65 + j]

    // f0 (block-uniform) in registers
    float f0[IND];
#pragma unroll
    for (int c = 0; c < IND; ++c) f0[c] = features[b * (NT * IND) + c];

    float base[30];
#pragma unroll
    for (int i = 0; i < 30; ++i) base[i] = 0.f;

    for (int tile = 0; tile < 4; ++tile) {
        const int t0 = tile * 64;
        // ---- load feature rows t0..t0+64 (row 256 clamped; inc forced 0 there) ----
        for (int e = tid; e < 65 * IND; e += 256) {
            int row = t0 + e / IND;
            int col = e % IND;
            if (row > NT - 1) row = NT - 1;
            sFt[e] = features[b * (NT * IND) + row * IND + col];
        }
        __syncthreads();   // Ba

        const int r = t0 + l;     // global step / output-row index
        float rf = (float)r;
        float fr[IND], rel[IND], inc[IND];
#pragma unroll
        for (int c = 0; c < IND; ++c) fr[c] = sFt[l * IND + c];
#pragma unroll
        for (int c = 0; c < IND; ++c) rel[c] = fr[c] - f0[c];
        {
            bool last = (r >= NT - 1);
#pragma unroll
            for (int c = 0; c < IND; ++c)
                inc[c] = last ? 0.f : (sFt[(l + 1) * IND + c] - fr[c]);
        }

        // ---- build this wave's 30-component payload slice ----
        float p[30], own[30];
        if (wu == 0) {
#pragma unroll
            for (int c = 0; c < 10; ++c) p[c] = rf * inc[c];
#pragma unroll
            for (int i = 0; i < 10; ++i) p[10 + i] = rel[i];
#pragma unroll
            for (int c = 0; c < 10; ++c) p[20 + c] = rel[0] * inc[c];
        } else {
            const int i0 = 3 * wu - 2;   // C rows: w1->1..3, w2->4..6, w3->7..9
#pragma unroll
            for (int q = 0; q < 30; ++q) {
                int i = i0 + q / 10, c = q % 10;
                p[q] = rel[i] * inc[c];
            }
        }
#pragma unroll
        for (int i = 0; i < 30; ++i) own[i] = p[i];

        // ---- inclusive wave scan (Hillis-Steele, 6 rounds) ----
#pragma unroll
        for (int dsh = 0; dsh < 6; ++dsh) {
            const int d = 1 << dsh;
            bool ok = (l >= d);
#pragma unroll
            for (int i = 0; i < 30; ++i) {
                float v = __shfl_up(p[i], d, 64);
                if (ok) p[i] += v;
            }
        }
        // tile totals (lane 63) broadcast for the carry
        float tot[30];
#pragma unroll
        for (int i = 0; i < 30; ++i) tot[i] = __shfl(p[i], 63, 64);

        float inv_r = (r > 0) ? 1.f / rf : 0.f;
        // exclusive-in-t global prefix, scaled by inv_k on A,B sections (k<20)
#pragma unroll
        for (int i = 0; i < 30; ++i) {
            float v = base[i] + p[i] - own[i];
            if (wu == 0 && i < 20) v *= inv_r;
            sP[(30 * wu + i) * 65 + l] = v;
        }
#pragma unroll
        for (int i = 0; i < 30; ++i) base[i] += tot[i];
        __syncthreads();   // Bb: sP ready

        // ---- j-phase: this wave handles 16 output columns ----
        const int jbase = __builtin_amdgcn_readfirstlane(16 * wu);
        float accA[16], accB[16], accC[16], ddv[16];
#pragma unroll
        for (int j = 0; j < 16; ++j) { accA[j] = 0.f; accB[j] = 0.f; accC[j] = 0.f; ddv[j] = 0.f; }

        for (int cc = 0; cc < 4; ++cc) {
            const int k0 = 30 * cc;
            float Pv[30];
#pragma unroll
            for (int i = 0; i < 30; ++i) Pv[i] = sP[(k0 + i) * 65 + l];
#pragma unroll
            for (int j = 0; j < 16; ++j) {
                const float* wp = Wr + (jbase + j) * WPJ;   // uniform -> s_load
#pragma unroll
                for (int i = 0; i < 30; ++i) {
                    accA[j] = fmaf(Pv[i], wp[k0 + i], accA[j]);
                    accB[j] = fmaf(Pv[i], wp[120 + k0 + i], accB[j]);
                    accC[j] = fmaf(Pv[i], wp[240 + k0 + i], accC[j]);
                }
                if (cc == 0) {
                    float dd = 0.f;
#pragma unroll
                    for (int i = 0; i < 10; ++i) dd = fmaf(Pv[i], wp[360 + i], dd);
                    dd = fmaf(Pv[10], wp[370], dd);
#pragma unroll
                    for (int i = 0; i < 5; ++i) dd = fmaf(Pv[20 + i], wp[371 + i], dd);
                    ddv[j] = dd;
                }
            }
        }

        // ---- finalize + staged store ----
        {
            float tt = 0.5f * (rf - 1.f) * inv_r;
            float gate = (r > 0) ? 1.f : 0.f;
            float r0 = rel[0], r1 = rel[1], r2 = rel[2];
#pragma unroll
            for (int j = 0; j < 16; ++j) {
                const float* wp = Wr + (jbase + j) * WPJ;
                float ds = accA[j] + tt * wp[396];
                float db = accB[j] + tt * wp[397];
                float dc = accC[j] + tt * wp[398];
                float dd = ddv[j] + tt * wp[399];
                float pre = ds + r0 * db + r1 * dc + r2 * dd;
                pre = fmaf(gate, wp[400], pre);
#pragma unroll
                for (int c = 0; c < 10; ++c) pre = fmaf(rel[c], wp[376 + c], pre);
#pragma unroll
                for (int c = 0; c < 10; ++c) pre = fmaf(fr[c], wp[386 + c], pre);
                pre += wp[401];
                sPre[l * 65 + jbase + j] = pre;
            }
        }
        __syncthreads();   // Bc: sPre ready (also orders sP reads vs next scan)

        // coalesced copy-out
        {
            float* op = pre1 + b * (NT * HID) + t0 * HID;
            for (int e = tid; e < 64 * 64; e += 256)
                op[e] = sPre[(e >> 6) * 65 + (e & 63)];
        }
        // next tile's sFt/sP writes are ordered by Ba/Bb; sPre next write after Bb.
    }
}

// ---------------------------------------------------------------------------
// Kernel B (unchanged from r5): per-batch sequential scan, one wave per batch.
// ---------------------------------------------------------------------------
template <int CTRL, int RMASK>
__device__ __forceinline__ float dpp_add(float x) {
    int v = __builtin_amdgcn_update_dpp(0, __float_as_int(x), CTRL, RMASK, 0xf, false);
    return x + __int_as_float(v);
}

#define W2_EACH(X) X(0) X(1) X(2) X(3) X(4) X(5) X(6) X(7) \
    X(8) X(9) X(10) X(11) X(12) X(13) X(14) X(15)

__global__ __launch_bounds__(64, 1) void scan_kernel(
    const float* __restrict__ pre1, const float* __restrict__ W1,
    const float* __restrict__ W2, const float* __restrict__ b2,
    const float* __restrict__ W3, const float* __restrict__ b3,
    float* __restrict__ out) {
    const int b = blockIdx.x;
    const int j = threadIdx.x;

    __shared__ __align__(16) float sH[64];

#define DECLW(q) float4 w2_##q = make_float4( \
        W2[(4*(q)+0)*64 + j], W2[(4*(q)+1)*64 + j], \
        W2[(4*(q)+2)*64 + j], W2[(4*(q)+3)*64 + j]);
    W2_EACH(DECLW)
#undef DECLW
    float w1l = W1[522 * 64 + j];
    float b2j = b2[j], w3j = W3[j], b3v = b3[0];

    const float* pb_ = pre1 + b * (NT * HID);
    float delta = 0.f;
    float outbuf = 0.f;

#define GEMVQ(q) { float4 h4 = *(const float4*)&sH[4*(q)]; \
        a0 = fmaf(h4.x, w2_##q.x, a0); a1 = fmaf(h4.y, w2_##q.y, a1); \
        a2 = fmaf(h4.z, w2_##q.z, a2); a3 = fmaf(h4.w, w2_##q.w, a3); }

#define SCAN_STEP(pv, mm) { \
        float h1 = fmaxf(fmaf(delta, w1l, (pv)), 0.f); \
        sH[j] = h1; \
        __syncthreads(); \
        float a0 = 0.f, a1 = 0.f, a2 = 0.f, a3 = 0.f; \
        W2_EACH(GEMVQ) \
        __syncthreads(); \
        float h2 = fmaxf((a0 + a1) + (a2 + a3) + b2j, 0.f); \
        float qv = h2 * w3j; \
        qv = dpp_add<0x111, 0xf>(qv); \
        qv = dpp_add<0x112, 0xf>(qv); \
        qv = dpp_add<0x114, 0xf>(qv); \
        qv = dpp_add<0x118, 0xf>(qv); \
        qv = dpp_add<0x142, 0xa>(qv); \
        qv = dpp_add<0x143, 0xc>(qv); \
        float tot = __int_as_float(__builtin_amdgcn_readlane(__float_as_int(qv), 63)); \
        delta = tot + b3v; \
        if (j == ((mm) & 63)) outbuf = delta; \
        if (((mm) & 63) == 63) out[b * NT + ((mm) & ~63) + j] = outbuf; }

    float r0 = pb_[0 * 64 + j], r1 = pb_[1 * 64 + j], r2 = pb_[2 * 64 + j],
          r3 = pb_[3 * 64 + j], r4 = pb_[4 * 64 + j], r5 = pb_[5 * 64 + j],
          r6 = pb_[6 * 64 + j], r7 = pb_[7 * 64 + j];
    for (int g = 0; g < NT; g += 8) {
        int nb = g + 8;
        float n0 = pb_[min(nb + 0, NT - 1) * 64 + j];
        float n1 = pb_[min(nb + 1, NT - 1) * 64 + j];
        float n2 = pb_[min(nb + 2, NT - 1) * 64 + j];
        float n3 = pb_[min(nb + 3, NT - 1) * 64 + j];
        float n4 = pb_[min(nb + 4, NT - 1) * 64 + j];
        float n5 = pb_[min(nb + 5, NT - 1) * 64 + j];
        float n6 = pb_[min(nb + 6, NT - 1) * 64 + j];
        float n7 = pb_[min(nb + 7, NT - 1) * 64 + j];
        SCAN_STEP(r0, g + 0)
        SCAN_STEP(r1, g + 1)
        SCAN_STEP(r2, g + 2)
        SCAN_STEP(r3, g + 3)
        SCAN_STEP(r4, g + 4)
        SCAN_STEP(r5, g + 5)
        SCAN_STEP(r6, g + 6)
        SCAN_STEP(r7, g + 7)
        r0 = n0; r1 = n1; r2 = n2; r3 = n3; r4 = n4; r5 = n5; r6 = n6; r7 = n7;
    }
#undef SCAN_STEP
#undef GEMVQ
}

// ---------------------------------------------------------------------------
// Fallback (round-1 fused kernel) if workspace is too small for pre1.
// ---------------------------------------------------------------------------
__global__ __launch_bounds__(256) void logsig_hedge_fallback(
    const float* __restrict__ features, const float* __restrict__ W1,
    const float* __restrict__ b1, const float* __restrict__ W2,
    const float* __restrict__ b2, const float* __restrict__ W3,
    const float* __restrict__ b3, float* __restrict__ out) {
    const int b = blockIdx.x;
    const int tid = threadIdx.x;
    const int j = tid & 63;
    const int s = tid >> 6;

    __shared__ __align__(16) float sF[NT * IND];
    __shared__ __align__(16) float sSig[128];
    __shared__ float sA[IND], sB[IND], sC[IND * IND];
    __shared__ float sRel[IND];
    __shared__ __align__(16) float sPart[4 * 64];
    __shared__ __align__(16) float sH1[64];

    for (int idx = tid; idx < NT * IND; idx += 256)
        sF[idx] = features[b * (NT * IND) + idx];
    if (tid < 100) sC[tid] = 0.f;
    else if (tid < 110) sA[tid - 100] = 0.f;
    else if (tid < 120) sB[tid - 110] = 0.f;
    else if (tid >= 121 && tid < 128) sSig[tid] = 0.f;

    float vs[32], vb[32], vc[32];
#pragma unroll
    for (int mm = 0; mm < 32; ++mm) {
        int mp = 32 * s + mm;
        if (mp < 121) {
            vs[mm] = W1[(11 + mp) * 64 + j] + W1[(132 + mp) * 64 + j];
            vb[mm] = W1[(253 + mp) * 64 + j];
            vc[mm] = W1[(374 + mp) * 64 + j];
        } else { vs[mm] = 0.f; vb[mm] = 0.f; vc[mm] = 0.f; }
    }
    float ex[17];
#pragma unroll
    for (int q = 0; q < 17; ++q) ex[q] = 0.f;
    if (s == 1) {
#pragma unroll
        for (int q = 0; q < 11; ++q) ex[q] = W1[q * 64 + j];
    } else if (s == 2) {
#pragma unroll
        for (int q = 0; q < 10; ++q) ex[q] = W1[(512 + q) * 64 + j];
        ex[10] = b1[j];
    } else if (s == 3) {
#pragma unroll
        for (int q = 0; q < 17; ++q) ex[q] = W1[(495 + q) * 64 + j];
    }
    float w2p[16];
#pragma unroll
    for (int ii = 0; ii < 16; ++ii) w2p[ii] = W2[(16 * s + ii) * 64 + j];

    float w1l = 0.f, b2j = 0.f, w3j = 0.f, b3v = 0.f;
    if (s == 0) { w1l = W1[522 * 64 + j]; b2j = b2[j]; w3j = W3[j]; b3v = b3[0]; }
    float delta = 0.f;

    __syncthreads();

    for (int m = 0; m < NT; ++m) {
        if (m > 0) {
            if (tid < 100) {
                int i = tid / 10, c = tid % 10;
                float rp = sF[(m - 1) * 10 + i] - sF[i];
                float ic = sF[m * 10 + c] - sF[(m - 1) * 10 + c];
                sC[tid] += rp * ic;
            } else if (tid < 110) {
                int i = tid - 100;
                sA[i] += (float)(m - 1) * (sF[m * 10 + i] - sF[(m - 1) * 10 + i]);
            } else if (tid < 120) {
                int i = tid - 110;
                sB[i] += sF[(m - 1) * 10 + i] - sF[i];
            }
            __syncthreads();
            float inv_k = 1.0f / (float)m;
            if (tid == 0) sSig[0] = 0.5f * (float)(m - 1) * inv_k;
            else if (tid < 11) sSig[tid] = inv_k * sA[tid - 1];
            else if (tid < 121) {
                int i = tid / 11 - 1, c = tid % 11;
                sSig[tid] = (c == 0) ? inv_k * sB[i] : sC[i * 10 + (c - 1)];
            } else if (tid < 131) {
                int f = tid - 121;
                sRel[f] = sF[m * 10 + f] - sF[f];
            }
            __syncthreads();
        }
        float part = 0.f;
        if (m > 0) {
            float pa = 0.f, pb = 0.f, pc = 0.f;
#pragma unroll
            for (int q = 0; q < 8; ++q) {
                float4 sv = *(const float4*)&sSig[32 * s + 4 * q];
                pa = fmaf(sv.x, vs[4 * q + 0], pa);
                pb = fmaf(sv.x, vb[4 * q + 0], pb);
                pc = fmaf(sv.x, vc[4 * q + 0], pc);
                pa = fmaf(sv.y, vs[4 * q + 1], pa);
                pb = fmaf(sv.y, vb[4 * q + 1], pb);
                pc = fmaf(sv.y, vc[4 * q + 1], pc);
                pa = fmaf(sv.z, vs[4 * q + 2], pa);
                pb = fmaf(sv.z, vb[4 * q + 2], pb);
                pc = fmaf(sv.z, vc[4 * q + 2], pc);
                pa = fmaf(sv.w, vs[4 * q + 3], pa);
                pb = fmaf(sv.w, vb[4 * q + 3], pb);
                pc = fmaf(sv.w, vc[4 * q + 3], pc);
            }
            part = pa + sRel[0] * pb + sRel[1] * pc;
            if (s == 3) {
                float pd = 0.f;
#pragma unroll
                for (int q = 0; q < 17; ++q) pd = fmaf(sSig[q], ex[q], pd);
                part = fmaf(sRel[2], pd, part);
            }
            if (s == 1) {
                part += ex[0];
#pragma unroll
                for (int i = 0; i < 10; ++i) part = fmaf(sRel[i], ex[1 + i], part);
            }
        }
        if (s == 2) {
            float pf = ex[10];
#pragma unroll
            for (int f = 0; f < 10; ++f) pf = fmaf(sF[m * 10 + f], ex[f], pf);
            part += pf;
        }
        sPart[s * 64 + j] = part;
        __syncthreads();
        if (s == 0) {
            float x = sPart[j] + sPart[64 + j] + sPart[128 + j] + sPart[192 + j];
            sH1[j] = fmaxf(fmaf(delta, w1l, x), 0.f);
        }
        __syncthreads();
        {
            float hp = 0.f;
#pragma unroll
            for (int q = 0; q < 4; ++q) {
                float4 hv = *(const float4*)&sH1[16 * s + 4 * q];
                hp = fmaf(hv.x, w2p[4 * q + 0], hp);
                hp = fmaf(hv.y, w2p[4 * q + 1], hp);
                hp = fmaf(hv.z, w2p[4 * q + 2], hp);
                hp = fmaf(hv.w, w2p[4 * q + 3], hp);
            }
            sPart[s * 64 + j] = hp;
        }
        __syncthreads();
        if (s == 0) {
            float x2 = sPart[j] + sPart[64 + j] + sPart[128 + j] + sPart[192 + j] + b2j;
            float h2 = fmaxf(x2, 0.f);
            float dv = h2 * w3j;
#pragma unroll
            for (int off = 32; off > 0; off >>= 1) dv += __shfl_xor(dv, off, 64);
            delta = dv + b3v;
            if (j == 0) out[b * NT + m] = delta;
        }
        __syncthreads();
    }
}

extern "C" void kernel_launch(void* const* d_in, const int* in_sizes, int n_in,
                              void* d_out, int out_size, void* d_ws, size_t ws_size,
                              hipStream_t stream) {
    const float* features = (const float*)d_in[0];
    const float* W1 = (const float*)d_in[1];
    const float* b1 = (const float*)d_in[2];
    const float* W2 = (const float*)d_in[3];
    const float* b2 = (const float*)d_in[4];
    const float* W3 = (const float*)d_in[5];
    const float* b3 = (const float*)d_in[6];
    float* out = (float*)d_out;

    const size_t wr_pad   = 103936;                                 // 256B-aligned
    const size_t pre_bytes = (size_t)NB * NT * HID * sizeof(float); // 64 MiB
    if (ws_size >= wr_pad + pre_bytes) {
        float* Wr = (float*)d_ws;
        float* pre1 = (float*)((char*)d_ws + wr_pad);
        pack_kernel<<<(64 * WPJ + 255) / 256, 256, 0, stream>>>(W1, b1, Wr);
        presig2_kernel<<<NB, 256, 0, stream>>>(features, Wr, pre1);
        scan_kernel<<<NB, 64, 0, stream>>>(pre1, W1, W2, b2, W3, b3, out);
    } else {
        logsig_hedge_fallback<<<NB, 256, 0, stream>>>(features, W1, b1, W2, b2, W3, b3, out);
    }
}